// Round 4
// baseline (58.230 us; speedup 1.0000x reference)
//
#include <hip/hip_runtime.h>
#include <math.h>

// DTW loss: B=64, N=512, D=2, L1 cost. Wave64 per batch, lane j owns cols
// [8j, 8j+8). Round-4: 4-deep LDS prefetch ring (kills lgkmcnt stalls),
// uniform exec-guarded step (ramp/drain via cndmask; DPP old=INF makes lane-0
// handling free), f32x2 cost math (v_pk_add_f32 opportunity), fused
// last-block mean reduction (saves 2nd dispatch).

typedef float f32x2 __attribute__((ext_vector_type(2)));

constexpr int NSEQ  = 512;
constexpr int BATCH = 64;
constexpr int P     = 8;     // columns per lane
constexpr int LANES = 64;
constexpr int FRONT = 64;            // front pad: ramp prefetch underflow
constexpr int XSN   = FRONT + 581;   // back pad: drain prefetch overflow (idx<=580)

__device__ __forceinline__ float dpp_wshr1_inf(float v) {
    // lane i <- lane i-1; lane 0 <- old = +inf (bound_ctrl=false)
    int r = __builtin_amdgcn_update_dpp(0x7F800000, __float_as_int(v),
                                        0x138, 0xF, 0xF, false);
    return __int_as_float(r);
}

__global__ __launch_bounds__(LANES) void dtw_fused(
    const float* __restrict__ pred,    // (B, N, 2) rows (x)
    const float* __restrict__ target,  // (B, N, 2) cols (y)
    float* __restrict__ out,           // scalar result
    float* __restrict__ ws)            // [0..63] per_batch, [64] flag
{
    const int b = blockIdx.x;
    const int j = threadIdx.x;

    __shared__ f32x2 xs[XSN];

    #pragma unroll
    for (int t = 0; t < NSEQ / LANES; ++t) {
        const int idx = t * LANES + j;
        xs[FRONT + idx] = reinterpret_cast<const f32x2*>(pred)[b * NSEQ + idx];
    }
    f32x2 nY[P];   // negated y pairs: cost = |x+nY| summed
    #pragma unroll
    for (int c = 0; c < P; ++c) {
        const f32x2 y = reinterpret_cast<const f32x2*>(target)[b * NSEQ + j * P + c];
        nY[c].x = -y.x; nY[c].y = -y.y;
    }
    __syncthreads();   // only barrier

    const float INF = __builtin_inff();
    float prev[P];
    #pragma unroll
    for (int c = 0; c < P; ++c) prev[c] = INF;
    float dg0 = INF;   // D[i-1][8j-1]; lane 0: INF forever

    // k = 0: lane 0 computes row-0 cumsum over its 8 cols. dg0 stays INF.
    if (j == 0) {
        const f32x2 x = xs[FRONT];
        f32x2 d0 = x + nY[0];
        float v = fabsf(d0.x) + fabsf(d0.y);
        prev[0] = v;
        #pragma unroll
        for (int c = 1; c < P; ++c) {
            f32x2 dc = x + nY[c];
            v += fabsf(dc.x) + fabsf(dc.y);
            prev[c] = v;
        }
    }

    // One DP step: v[c] = cost_c + min3(up=prev[c], diag=prev[c-1]|dg0, left).
    // INF identities fold row-0 cumsum into the same code. guard=true masks
    // prev[] writes to active lanes (0 <= k-j < 512).
    auto step = [&](float left, f32x2 x, int kk, bool guard) {
        float v_[P];
        {
            f32x2 d = x + nY[0];
            v_[0] = fabsf(d.x) + fabsf(d.y) + fminf(fminf(prev[0], dg0), left);
        }
        float pm1 = prev[0];
        #pragma unroll
        for (int c = 1; c < P; ++c) {
            f32x2 d = x + nY[c];
            const float pc = prev[c];
            v_[c] = fabsf(d.x) + fabsf(d.y) + fminf(fminf(pc, pm1), v_[c - 1]);
            pm1 = pc;
        }
        if (guard) {
            const bool act = (unsigned)(kk - j) < (unsigned)NSEQ;
            #pragma unroll
            for (int c = 0; c < P; ++c) prev[c] = act ? v_[c] : prev[c];
        } else {
            #pragma unroll
            for (int c = 0; c < P; ++c) prev[c] = v_[c];
        }
        dg0 = left;   // lane 0: dpp injects INF, so dg0 stays INF; correct.
    };

    // Prefetch ring: r0..r3 hold xs[k4+d - j] for the current 4-step block.
    f32x2 r0, r1, r2, r3;
    {
        const int base = FRONT + 1 - j;
        r0 = xs[base]; r1 = xs[base + 1]; r2 = xs[base + 2]; r3 = xs[base + 3];
    }

    auto block4 = [&](int k4, bool guard) {
        const int base = FRONT + k4 + 4 - j;    // next block's rows (pad-covered)
        const f32x2 n0 = xs[base],     n1 = xs[base + 1];
        const f32x2 n2 = xs[base + 2], n3 = xs[base + 3];
        float left;
        left = dpp_wshr1_inf(prev[P - 1]); step(left, r0, k4 + 0, guard);
        left = dpp_wshr1_inf(prev[P - 1]); step(left, r1, k4 + 1, guard);
        left = dpp_wshr1_inf(prev[P - 1]); step(left, r2, k4 + 2, guard);
        left = dpp_wshr1_inf(prev[P - 1]); step(left, r3, k4 + 3, guard);
        r0 = n0; r1 = n1; r2 = n2; r3 = n3;
    };

    #pragma unroll 1
    for (int k4 = 1; k4 <= 61; k4 += 4)   block4(k4, true);    // ramp  k=1..64
    #pragma unroll 1
    for (int k4 = 65; k4 <= 505; k4 += 4) block4(k4, false);   // steady k=65..508
    #pragma unroll 1
    for (int k4 = 509; k4 <= 573; k4 += 4) block4(k4, true);   // drain k=509..576

    // ---- fused mean reduction: last block to finish sums per_batch ----
    float* per_batch = ws;
    unsigned* flag = reinterpret_cast<unsigned*>(ws + BATCH);
    if (j == LANES - 1) per_batch[b] = prev[P - 1];   // D[N-1][N-1]
    __threadfence();
    unsigned old = 0;
    if (j == 0) old = atomicAdd(flag, 1u);
    old = __shfl(old, 0);
    if (old == BATCH - 1) {
        __threadfence();
        float v = per_batch[j];   // 64 lanes == 64 batches
        #pragma unroll
        for (int off = 32; off >= 1; off >>= 1) v += __shfl_down(v, off);
        if (j == 0) out[0] = v * (1.0f / BATCH);
    }
}

extern "C" void kernel_launch(void* const* d_in, const int* in_sizes, int n_in,
                              void* d_out, int out_size, void* d_ws, size_t ws_size,
                              hipStream_t stream) {
    const float* pred   = (const float*)d_in[0];
    const float* target = (const float*)d_in[1];
    float* out = (float*)d_out;
    float* ws  = (float*)d_ws;

    // reset the completion counter each call (graph-capturable)
    hipMemsetAsync((char*)d_ws + BATCH * sizeof(float), 0, sizeof(unsigned), stream);
    dtw_fused<<<BATCH, LANES, 0, stream>>>(pred, target, out, ws);
}